// Round 3
// baseline (661.887 us; speedup 1.0000x reference)
//
#include <hip/hip_runtime.h>
#include <hip/hip_bf16.h>

// Problem constants (from reference)
#define N_NODES 4096
#define IN_DIM  512
#define HID_DIM 256
#define OUT_DIM 64
#define PROP_STEP 10
#define MAX_DEG 128            // mean degree ~41, max row degree ~<80; 128 is safe
#define LAM_CONST (1.0f/0.9f - 1.0f)
#define SCAD_A 3.7f

__device__ __forceinline__ float wave_reduce_add(float v) {
#pragma unroll
    for (int off = 32; off > 0; off >>= 1) v += __shfl_xor(v, off, 64);
    return v;
}

// ---------------------------------------------------------------------------
// Build ELL adjacency + degree stats from dense fp32 A (values exactly 0/1,
// zero diagonal). One block per row; single pass over the 64 MB matrix.
// D = deg + 1 (add_loops). Diagonal never enters the edge list because
// W*(1-eye) zeroes it in the reference.
// ---------------------------------------------------------------------------
__global__ __launch_bounds__(256) void build_graph(
    const float* __restrict__ A, int* __restrict__ ell, int* __restrict__ deg,
    float* __restrict__ invD, float* __restrict__ invDsq)
{
    int i = blockIdx.x;
    int t = threadIdx.x;
    __shared__ int cnt;
    if (t == 0) cnt = 0;
    __syncthreads();
    const float4* row = (const float4*)(A + (size_t)i * N_NODES);  // 1024 float4 per row
    for (int q = t; q < N_NODES / 4; q += 256) {
        float4 v = row[q];
        if (v.x != 0.0f) { int p = atomicAdd(&cnt, 1); if (p < MAX_DEG) ell[i * MAX_DEG + p] = q * 4 + 0; }
        if (v.y != 0.0f) { int p = atomicAdd(&cnt, 1); if (p < MAX_DEG) ell[i * MAX_DEG + p] = q * 4 + 1; }
        if (v.z != 0.0f) { int p = atomicAdd(&cnt, 1); if (p < MAX_DEG) ell[i * MAX_DEG + p] = q * 4 + 2; }
        if (v.w != 0.0f) { int p = atomicAdd(&cnt, 1); if (p < MAX_DEG) ell[i * MAX_DEG + p] = q * 4 + 3; }
    }
    __syncthreads();
    if (t == 0) {
        int c = cnt;
        deg[i] = c > MAX_DEG ? MAX_DEG : c;
        float d = (float)(c + 1);
        invD[i] = 1.0f / d;
        invDsq[i] = rsqrtf(d);
    }
}

// ---------------------------------------------------------------------------
// H = relu(F @ W1 + b1) : [4096,512] x [512,256], fp32.
// 64x64 tile per 256-thread block, 4x4 per thread, TK=16 LDS staging.
// ---------------------------------------------------------------------------
__global__ __launch_bounds__(256) void mlp1(
    const float* __restrict__ F, const float* __restrict__ W1,
    const float* __restrict__ b1, float* __restrict__ H)
{
    __shared__ float sA[16][64];   // [k][m]
    __shared__ float sB[16][64];   // [k][n]
    int t  = threadIdx.x;
    int m0 = blockIdx.x * 64;
    int n0 = blockIdx.y * 64;
    int tm = (t & 15) * 4;
    int tn = (t >> 4) * 4;
    // loader coords
    int ar = t >> 2;            // 0..63 m-row
    int ac = (t & 3) * 4;       // 0,4,8,12 k-offset
    int br = t >> 4;            // 0..15 k-row
    int bc = (t & 15) * 4;      // 0..60 n-col
    float acc[4][4] = {};
    for (int kc = 0; kc < IN_DIM; kc += 16) {
        float4 va = *(const float4*)(F  + (size_t)(m0 + ar) * IN_DIM + kc + ac);
        float4 vb = *(const float4*)(W1 + (size_t)(kc + br) * HID_DIM + n0 + bc);
        __syncthreads();   // previous compute done before overwriting LDS
        sA[ac + 0][ar] = va.x;
        sA[ac + 1][ar] = va.y;
        sA[ac + 2][ar] = va.z;
        sA[ac + 3][ar] = va.w;
        *(float4*)&sB[br][bc] = vb;
        __syncthreads();
#pragma unroll
        for (int k = 0; k < 16; k++) {
            float4 a = *(const float4*)&sA[k][tm];
            float4 b = *(const float4*)&sB[k][tn];
            acc[0][0] += a.x * b.x; acc[0][1] += a.x * b.y; acc[0][2] += a.x * b.z; acc[0][3] += a.x * b.w;
            acc[1][0] += a.y * b.x; acc[1][1] += a.y * b.y; acc[1][2] += a.y * b.z; acc[1][3] += a.y * b.w;
            acc[2][0] += a.z * b.x; acc[2][1] += a.z * b.y; acc[2][2] += a.z * b.z; acc[2][3] += a.z * b.w;
            acc[3][0] += a.w * b.x; acc[3][1] += a.w * b.y; acc[3][2] += a.w * b.z; acc[3][3] += a.w * b.w;
        }
    }
    float4 bias = *(const float4*)(b1 + n0 + tn);
#pragma unroll
    for (int r = 0; r < 4; r++) {
        float4 o;
        o.x = fmaxf(acc[r][0] + bias.x, 0.0f);
        o.y = fmaxf(acc[r][1] + bias.y, 0.0f);
        o.z = fmaxf(acc[r][2] + bias.z, 0.0f);
        o.w = fmaxf(acc[r][3] + bias.w, 0.0f);
        *(float4*)&H[(size_t)(m0 + tm + r) * HID_DIM + n0 + tn] = o;
    }
}

// ---------------------------------------------------------------------------
// F0 = H @ W2 + b2 : [4096,256] x [256,64]. One wave per row, lane = out col.
// ---------------------------------------------------------------------------
__global__ __launch_bounds__(256) void mlp2(
    const float* __restrict__ H, const float* __restrict__ W2,
    const float* __restrict__ b2, float* __restrict__ F0)
{
    int wid = threadIdx.x >> 6, lane = threadIdx.x & 63;
    int row = blockIdx.x * 4 + wid;
    const float* h = H + (size_t)row * HID_DIM;
    float acc = b2[lane];
#pragma unroll 4
    for (int k = 0; k < HID_DIM; k++) {
        acc += h[k] * W2[k * OUT_DIM + lane];
    }
    F0[(size_t)row * OUT_DIM + lane] = acc;
}

// ---------------------------------------------------------------------------
// Fu = normalize(Fc / D_sq) rows. One wave per row (64 dims = 64 lanes).
// ---------------------------------------------------------------------------
__global__ __launch_bounds__(256) void normalize_rows(
    const float* __restrict__ Fc, const float* __restrict__ invDsq, float* __restrict__ Fu)
{
    int wid = threadIdx.x >> 6, lane = threadIdx.x & 63;
    int row = blockIdx.x * 4 + wid;
    float v = Fc[(size_t)row * OUT_DIM + lane] * invDsq[row];
    float nrm = sqrtf(wave_reduce_add(v * v));
    Fu[(size_t)row * OUT_DIM + lane] = v / fmaxf(nrm, 1e-12f);
}

// ---------------------------------------------------------------------------
// One propagation step, sparse. One wave per row:
//   per edge (i,j): y = 1 - <Fu_i,Fu_j>;  w = SCAD(y);
//   acc += w * D_j^-1/2 * Fc[j];  qsum += w
//   F_new = (acc * D_i^-1/2 + lam*F0) / (qsum/D_i + lam)
// ---------------------------------------------------------------------------
__global__ __launch_bounds__(256) void propagate(
    const float* __restrict__ Fc, const float* __restrict__ Fu, const float* __restrict__ F0,
    const int* __restrict__ ell, const int* __restrict__ deg,
    const float* __restrict__ invD, const float* __restrict__ invDsq,
    const float* __restrict__ raw_gamma, int step, float* __restrict__ Fnext)
{
    int wid = threadIdx.x >> 6, lane = threadIdx.x & 63;
    int row = blockIdx.x * 4 + wid;
    float gamma   = 2.0f / (1.0f + expf(-raw_gamma[step]));
    float lam_k   = fmaxf(gamma / SCAD_A, 1e-8f);
    float tt      = SCAD_A * lam_k;
    const float inv_am1 = 1.0f / (SCAD_A - 1.0f);

    float fui = Fu[(size_t)row * OUT_DIM + lane];
    float acc = 0.0f, qsum = 0.0f;
    int dg = deg[row];
    const int* nb = ell + (size_t)row * MAX_DEG;
    for (int e = 0; e < dg; e++) {
        int j = nb[e];
        float p = fui * Fu[(size_t)j * OUT_DIM + lane];
        p = wave_reduce_add(p);                      // full cosine dot, result in all lanes
        float y = 1.0f - p;
        float w = (y <= lam_k) ? 1.0f : ((y <= tt) ? (tt - y) * inv_am1 / y : 0.0f);
        if (w > 0.0f) {                              // wave-uniform branch
            acc  += (w * invDsq[j]) * Fc[(size_t)j * OUT_DIM + lane];
            qsum += w;
        }
    }
    float Qh  = qsum * invD[row] + LAM_CONST;
    float res = (acc * invDsq[row] + LAM_CONST * F0[(size_t)row * OUT_DIM + lane]) / Qh;
    Fnext[(size_t)row * OUT_DIM + lane] = res;
}

// ---------------------------------------------------------------------------
extern "C" void kernel_launch(void* const* d_in, const int* in_sizes, int n_in,
                              void* d_out, int out_size, void* d_ws, size_t ws_size,
                              hipStream_t stream)
{
    const float* A  = (const float*)d_in[0];
    const float* F  = (const float*)d_in[1];
    const float* W1 = (const float*)d_in[2];
    const float* b1 = (const float*)d_in[3];
    const float* W2 = (const float*)d_in[4];
    const float* b2 = (const float*)d_in[5];
    const float* rg = (const float*)d_in[6];
    float* out = (float*)d_out;   // reference output dtype is float32

    // workspace layout (~10.1 MB total)
    char* p = (char*)d_ws;
    float* H      = (float*)p; p += (size_t)N_NODES * HID_DIM * 4;   // 4 MB
    float* F0     = (float*)p; p += (size_t)N_NODES * OUT_DIM * 4;   // 1 MB
    float* B0     = (float*)p; p += (size_t)N_NODES * OUT_DIM * 4;   // 1 MB
    float* B1     = (float*)p; p += (size_t)N_NODES * OUT_DIM * 4;   // 1 MB
    float* Fu     = (float*)p; p += (size_t)N_NODES * OUT_DIM * 4;   // 1 MB
    float* invD   = (float*)p; p += (size_t)N_NODES * 4;
    float* invDsq = (float*)p; p += (size_t)N_NODES * 4;
    int*   deg    = (int*)p;   p += (size_t)N_NODES * 4;
    int*   ell    = (int*)p;   p += (size_t)N_NODES * MAX_DEG * 4;   // 2 MB

    build_graph<<<N_NODES, 256, 0, stream>>>(A, ell, deg, invD, invDsq);
    mlp1<<<dim3(N_NODES / 64, HID_DIM / 64), 256, 0, stream>>>(F, W1, b1, H);
    mlp2<<<N_NODES / 4, 256, 0, stream>>>(H, W2, b2, F0);

    float* bufs[2] = {B0, B1};
    const float* src = F0;
    for (int k = 0; k < PROP_STEP; k++) {
        // last step writes fp32 straight into d_out
        float* dst = (k == PROP_STEP - 1) ? out : bufs[k & 1];
        normalize_rows<<<N_NODES / 4, 256, 0, stream>>>(src, invDsq, Fu);
        propagate<<<N_NODES / 4, 256, 0, stream>>>(src, Fu, F0, ell, deg, invD, invDsq, rg, k, dst);
        src = dst;
    }
}

// Round 4
// 265.295 us; speedup vs baseline: 2.4949x; 2.4949x over previous
//
#include <hip/hip_runtime.h>
#include <hip/hip_bf16.h>

// Problem constants (from reference)
#define N_NODES 4096
#define IN_DIM  512
#define HID_DIM 256
#define OUT_DIM 64
#define PROP_STEP 10
#define MAX_DEG 128            // mean degree ~41; multiple of 8 for padded ELL
#define LAM_CONST (1.0f/0.9f - 1.0f)
#define SCAD_A 3.7f

__device__ __forceinline__ float wave_reduce_add(float v) {
#pragma unroll
    for (int off = 32; off > 0; off >>= 1) v += __shfl_xor(v, off, 64);
    return v;
}

// ---------------------------------------------------------------------------
// Build ELL adjacency + degree stats from dense fp32 A (values exactly 0/1,
// zero diagonal). One block per row. Pads each ELL row to a multiple of 8
// with self-index (masked out in propagate via e<deg).
// ---------------------------------------------------------------------------
__global__ __launch_bounds__(256) void build_graph(
    const float* __restrict__ A, int* __restrict__ ell, int* __restrict__ deg,
    float* __restrict__ invD, float* __restrict__ invDsq)
{
    int i = blockIdx.x;
    int t = threadIdx.x;
    __shared__ int cnt;
    if (t == 0) cnt = 0;
    __syncthreads();
    const float4* row = (const float4*)(A + (size_t)i * N_NODES);
    for (int q = t; q < N_NODES / 4; q += 256) {
        float4 v = row[q];
        if (v.x != 0.0f) { int p = atomicAdd(&cnt, 1); if (p < MAX_DEG) ell[i * MAX_DEG + p] = q * 4 + 0; }
        if (v.y != 0.0f) { int p = atomicAdd(&cnt, 1); if (p < MAX_DEG) ell[i * MAX_DEG + p] = q * 4 + 1; }
        if (v.z != 0.0f) { int p = atomicAdd(&cnt, 1); if (p < MAX_DEG) ell[i * MAX_DEG + p] = q * 4 + 2; }
        if (v.w != 0.0f) { int p = atomicAdd(&cnt, 1); if (p < MAX_DEG) ell[i * MAX_DEG + p] = q * 4 + 3; }
    }
    __syncthreads();
    if (t == 0) {
        int c = cnt;
        if (c > MAX_DEG) c = MAX_DEG;
        deg[i] = c;
        int pad = (c + 7) & ~7;
        if (pad > MAX_DEG) pad = MAX_DEG;
        for (int p = c; p < pad; p++) ell[i * MAX_DEG + p] = i;  // self pad, masked later
        float d = (float)(cnt + 1);   // true degree + self loop
        invD[i] = 1.0f / d;
        invDsq[i] = rsqrtf(d);
    }
}

// ---------------------------------------------------------------------------
// H = relu(F @ W1 + b1) : [4096,512] x [512,256], fp32.
// ---------------------------------------------------------------------------
__global__ __launch_bounds__(256) void mlp1(
    const float* __restrict__ F, const float* __restrict__ W1,
    const float* __restrict__ b1, float* __restrict__ H)
{
    __shared__ float sA[16][64];   // [k][m]
    __shared__ float sB[16][64];   // [k][n]
    int t  = threadIdx.x;
    int m0 = blockIdx.x * 64;
    int n0 = blockIdx.y * 64;
    int tm = (t & 15) * 4;
    int tn = (t >> 4) * 4;
    int ar = t >> 2;
    int ac = (t & 3) * 4;
    int br = t >> 4;
    int bc = (t & 15) * 4;
    float acc[4][4] = {};
    for (int kc = 0; kc < IN_DIM; kc += 16) {
        float4 va = *(const float4*)(F  + (size_t)(m0 + ar) * IN_DIM + kc + ac);
        float4 vb = *(const float4*)(W1 + (size_t)(kc + br) * HID_DIM + n0 + bc);
        __syncthreads();
        sA[ac + 0][ar] = va.x;
        sA[ac + 1][ar] = va.y;
        sA[ac + 2][ar] = va.z;
        sA[ac + 3][ar] = va.w;
        *(float4*)&sB[br][bc] = vb;
        __syncthreads();
#pragma unroll
        for (int k = 0; k < 16; k++) {
            float4 a = *(const float4*)&sA[k][tm];
            float4 b = *(const float4*)&sB[k][tn];
            acc[0][0] += a.x * b.x; acc[0][1] += a.x * b.y; acc[0][2] += a.x * b.z; acc[0][3] += a.x * b.w;
            acc[1][0] += a.y * b.x; acc[1][1] += a.y * b.y; acc[1][2] += a.y * b.z; acc[1][3] += a.y * b.w;
            acc[2][0] += a.z * b.x; acc[2][1] += a.z * b.y; acc[2][2] += a.z * b.z; acc[2][3] += a.z * b.w;
            acc[3][0] += a.w * b.x; acc[3][1] += a.w * b.y; acc[3][2] += a.w * b.z; acc[3][3] += a.w * b.w;
        }
    }
    float4 bias = *(const float4*)(b1 + n0 + tn);
#pragma unroll
    for (int r = 0; r < 4; r++) {
        float4 o;
        o.x = fmaxf(acc[r][0] + bias.x, 0.0f);
        o.y = fmaxf(acc[r][1] + bias.y, 0.0f);
        o.z = fmaxf(acc[r][2] + bias.z, 0.0f);
        o.w = fmaxf(acc[r][3] + bias.w, 0.0f);
        *(float4*)&H[(size_t)(m0 + tm + r) * HID_DIM + n0 + tn] = o;
    }
}

// ---------------------------------------------------------------------------
// F0 = H @ W2 + b2, fused with first normalize: Fn0 = F0*invDsq, Fu0 = unit(Fn0).
// One wave per row, lane = out col.
// ---------------------------------------------------------------------------
__global__ __launch_bounds__(256) void mlp2(
    const float* __restrict__ H, const float* __restrict__ W2,
    const float* __restrict__ b2, const float* __restrict__ invDsq,
    float* __restrict__ F0, float* __restrict__ Fu0, float* __restrict__ Fn0)
{
    int wid = threadIdx.x >> 6, lane = threadIdx.x & 63;
    int row = blockIdx.x * 4 + wid;
    const float* h = H + (size_t)row * HID_DIM;
    float acc = b2[lane];
    for (int k = 0; k < HID_DIM; k += 4) {
        float4 hv = *(const float4*)(h + k);
        acc += hv.x * W2[(k + 0) * OUT_DIM + lane];
        acc += hv.y * W2[(k + 1) * OUT_DIM + lane];
        acc += hv.z * W2[(k + 2) * OUT_DIM + lane];
        acc += hv.w * W2[(k + 3) * OUT_DIM + lane];
    }
    size_t o = (size_t)row * OUT_DIM + lane;
    F0[o] = acc;
    float fn = acc * invDsq[row];
    float nrm = sqrtf(wave_reduce_add(fn * fn));
    Fn0[o] = fn;
    Fu0[o] = fn / fmaxf(nrm, 1e-12f);
}

// ---------------------------------------------------------------------------
// One propagation step. One wave per row; 8 lanes per edge (8 edges in
// flight); lane sl=lane&7 owns features [8sl, 8sl+8).
//   per edge (i,j): y = 1 - <Fu_i,Fu_j>; w = SCAD(y)*(e<deg)
//   acc += w * Fn[j]   (Fn = D^-1/2-scaled features)
//   res = (acc*D_i^-1/2 + lam*F0) / (qsum/D_i + lam)
// Emits next-step Fu/Fn in the same kernel (whole row lives in this wave).
// ---------------------------------------------------------------------------
__global__ __launch_bounds__(256) void propagate(
    const float* __restrict__ FuIn, const float* __restrict__ FnIn,
    const float* __restrict__ F0,
    const int* __restrict__ ell, const int* __restrict__ deg,
    const float* __restrict__ invD, const float* __restrict__ invDsq,
    const float* __restrict__ raw_gamma, int step,
    float* __restrict__ FuOut, float* __restrict__ FnOut,
    float* __restrict__ FcOut, int writeNext, int writeOut)
{
    int lane = threadIdx.x & 63;
    int wid  = threadIdx.x >> 6;
    int row  = blockIdx.x * 4 + wid;
    int r    = __builtin_amdgcn_readfirstlane(row);
    int g    = lane >> 3;          // edge group 0..7
    int sl   = lane & 7;           // feature slice within group

    float gamma = 2.0f / (1.0f + expf(-raw_gamma[step]));
    float lam_k = fmaxf(gamma / SCAD_A, 1e-8f);
    float tt    = SCAD_A * lam_k;
    const float inv_am1 = 1.0f / (SCAD_A - 1.0f);

    const float4* ui4 = (const float4*)(FuIn + (size_t)r * OUT_DIM + sl * 8);
    float4 uia = ui4[0], uib = ui4[1];

    int dg = deg[r];
    int niter = (dg + 7) >> 3;
    const int* nb = ell + (size_t)r * MAX_DEG;

    float4 acca = {0.f, 0.f, 0.f, 0.f}, accb = {0.f, 0.f, 0.f, 0.f};
    float qsum = 0.0f;

    for (int it = 0; it < niter; ++it) {
        int e = it * 8 + g;
        int j = nb[e];                               // group-uniform
        const float4* uj4 = (const float4*)(FuIn + (size_t)j * OUT_DIM + sl * 8);
        const float4* nj4 = (const float4*)(FnIn + (size_t)j * OUT_DIM + sl * 8);
        float4 uja = uj4[0], ujb = uj4[1];
        float4 nja = nj4[0], njb = nj4[1];
        float p = uia.x * uja.x + uia.y * uja.y + uia.z * uja.z + uia.w * uja.w
                + uib.x * ujb.x + uib.y * ujb.y + uib.z * ujb.z + uib.w * ujb.w;
        p += __shfl_xor(p, 1, 64);
        p += __shfl_xor(p, 2, 64);
        p += __shfl_xor(p, 4, 64);                   // full dot in all 8 lanes of group
        float y = 1.0f - p;
        float w = (y <= lam_k) ? 1.0f : ((y <= tt) ? (tt - y) * inv_am1 / y : 0.0f);
        if (e >= dg) w = 0.0f;                       // padded entry
        acca.x += w * nja.x; acca.y += w * nja.y; acca.z += w * nja.z; acca.w += w * nja.w;
        accb.x += w * njb.x; accb.y += w * njb.y; accb.z += w * njb.z; accb.w += w * njb.w;
        qsum += w;
    }

    // cross-group reduction (8 groups hold disjoint edge subsets)
#pragma unroll
    for (int off = 8; off <= 32; off <<= 1) {
        acca.x += __shfl_xor(acca.x, off, 64); acca.y += __shfl_xor(acca.y, off, 64);
        acca.z += __shfl_xor(acca.z, off, 64); acca.w += __shfl_xor(acca.w, off, 64);
        accb.x += __shfl_xor(accb.x, off, 64); accb.y += __shfl_xor(accb.y, off, 64);
        accb.z += __shfl_xor(accb.z, off, 64); accb.w += __shfl_xor(accb.w, off, 64);
        qsum   += __shfl_xor(qsum,   off, 64);
    }

    float iDs = invDsq[r];
    float Qh  = qsum * invD[r] + LAM_CONST;
    float rQh = 1.0f / Qh;
    const float4* f04 = (const float4*)(F0 + (size_t)r * OUT_DIM + sl * 8);
    float4 f0a = f04[0], f0b = f04[1];
    float4 resa, resb;
    resa.x = (acca.x * iDs + LAM_CONST * f0a.x) * rQh;
    resa.y = (acca.y * iDs + LAM_CONST * f0a.y) * rQh;
    resa.z = (acca.z * iDs + LAM_CONST * f0a.z) * rQh;
    resa.w = (acca.w * iDs + LAM_CONST * f0a.w) * rQh;
    resb.x = (accb.x * iDs + LAM_CONST * f0b.x) * rQh;
    resb.y = (accb.y * iDs + LAM_CONST * f0b.y) * rQh;
    resb.z = (accb.z * iDs + LAM_CONST * f0b.z) * rQh;
    resb.w = (accb.w * iDs + LAM_CONST * f0b.w) * rQh;

    if (writeOut && lane < 8) {
        float4* o4 = (float4*)(FcOut + (size_t)r * OUT_DIM + sl * 8);
        o4[0] = resa; o4[1] = resb;
    }
    if (writeNext) {
        // next-step Fn/Fu for this row (all groups hold identical res)
        float4 fna, fnb;
        fna.x = resa.x * iDs; fna.y = resa.y * iDs; fna.z = resa.z * iDs; fna.w = resa.w * iDs;
        fnb.x = resb.x * iDs; fnb.y = resb.y * iDs; fnb.z = resb.z * iDs; fnb.w = resb.w * iDs;
        float ssq = fna.x * fna.x + fna.y * fna.y + fna.z * fna.z + fna.w * fna.w
                  + fnb.x * fnb.x + fnb.y * fnb.y + fnb.z * fnb.z + fnb.w * fnb.w;
        ssq += __shfl_xor(ssq, 1, 64);
        ssq += __shfl_xor(ssq, 2, 64);
        ssq += __shfl_xor(ssq, 4, 64);
        float inv_n = 1.0f / fmaxf(sqrtf(ssq), 1e-12f);
        if (lane < 8) {
            float4* fn4 = (float4*)(FnOut + (size_t)r * OUT_DIM + sl * 8);
            fn4[0] = fna; fn4[1] = fnb;
            float4 fua, fub;
            fua.x = fna.x * inv_n; fua.y = fna.y * inv_n; fua.z = fna.z * inv_n; fua.w = fna.w * inv_n;
            fub.x = fnb.x * inv_n; fub.y = fnb.y * inv_n; fub.z = fnb.z * inv_n; fub.w = fnb.w * inv_n;
            float4* fu4 = (float4*)(FuOut + (size_t)r * OUT_DIM + sl * 8);
            fu4[0] = fua; fu4[1] = fub;
        }
    }
}

// ---------------------------------------------------------------------------
extern "C" void kernel_launch(void* const* d_in, const int* in_sizes, int n_in,
                              void* d_out, int out_size, void* d_ws, size_t ws_size,
                              hipStream_t stream)
{
    const float* A  = (const float*)d_in[0];
    const float* F  = (const float*)d_in[1];
    const float* W1 = (const float*)d_in[2];
    const float* b1 = (const float*)d_in[3];
    const float* W2 = (const float*)d_in[4];
    const float* b2 = (const float*)d_in[5];
    const float* rg = (const float*)d_in[6];
    float* out = (float*)d_out;

    // workspace layout (~11.1 MB)
    char* p = (char*)d_ws;
    float* H      = (float*)p; p += (size_t)N_NODES * HID_DIM * 4;   // 4 MB
    float* F0     = (float*)p; p += (size_t)N_NODES * OUT_DIM * 4;   // 1 MB
    float* FuB[2]; FuB[0] = (float*)p; p += (size_t)N_NODES * OUT_DIM * 4;
                   FuB[1] = (float*)p; p += (size_t)N_NODES * OUT_DIM * 4;
    float* FnB[2]; FnB[0] = (float*)p; p += (size_t)N_NODES * OUT_DIM * 4;
                   FnB[1] = (float*)p; p += (size_t)N_NODES * OUT_DIM * 4;
    float* invD   = (float*)p; p += (size_t)N_NODES * 4;
    float* invDsq = (float*)p; p += (size_t)N_NODES * 4;
    int*   deg    = (int*)p;   p += (size_t)N_NODES * 4;
    int*   ell    = (int*)p;   p += (size_t)N_NODES * MAX_DEG * 4;   // 2 MB

    build_graph<<<N_NODES, 256, 0, stream>>>(A, ell, deg, invD, invDsq);
    mlp1<<<dim3(N_NODES / 64, HID_DIM / 64), 256, 0, stream>>>(F, W1, b1, H);
    mlp2<<<N_NODES / 4, 256, 0, stream>>>(H, W2, b2, invDsq, F0, FuB[0], FnB[0]);

    for (int k = 0; k < PROP_STEP; k++) {
        int in = k & 1, nx = (k + 1) & 1;
        int last = (k == PROP_STEP - 1);
        propagate<<<N_NODES / 4, 256, 0, stream>>>(
            FuB[in], FnB[in], F0, ell, deg, invD, invDsq, rg, k,
            FuB[nx], FnB[nx], out, !last, last);
    }
}